// Round 8
// baseline (162.594 us; speedup 1.0000x reference)
//
#include <hip/hip_runtime.h>

#define P_CNT 32768
#define D_DIM 256
#define B_SZ  256
#define NTHR  1024
#define NW    16
#define INVT  20.0f          // 1/TEMP
#define NEG_BIG -3.0e38f

typedef _Float16 half8  __attribute__((ext_vector_type(8)));
typedef _Float16 half4v __attribute__((ext_vector_type(4)));
typedef float    floatx4 __attribute__((ext_vector_type(4)));

// ---------------- block reduction helpers (1024 threads, wave64) ----------------
__device__ __forceinline__ float blockMax(float v, int tid, float* redW) {
#pragma unroll
  for (int off = 1; off < 64; off <<= 1) v = fmaxf(v, __shfl_xor(v, off));
  if ((tid & 63) == 0) redW[tid >> 6] = v;
  __syncthreads();
  float r = redW[0];
#pragma unroll
  for (int w = 1; w < NW; ++w) r = fmaxf(r, redW[w]);
  __syncthreads();
  return r;
}

__device__ __forceinline__ float blockSum(float v, int tid, float* redW) {
#pragma unroll
  for (int off = 1; off < 64; off <<= 1) v += __shfl_xor(v, off);
  if ((tid & 63) == 0) redW[tid >> 6] = v;
  __syncthreads();
  float r = 0.f;
#pragma unroll
  for (int w = 0; w < NW; ++w) r += redW[w];
  __syncthreads();
  return r;
}

__device__ __forceinline__ unsigned fkey(float v) {
  unsigned bu = __float_as_uint(v);
  return bu ^ ((unsigned)(((int)bu) >> 31) | 0x80000000u);
}

// ---------------- find the histogram bin holding the k-th largest ----------------
// On return: prefix/prevShift identify the bin (key>>prevShift == prefix), krem =
// rank of the target within the bin. Elements with key>>prevShift > prefix are
// exactly the (k - krem) elements strictly above the bin.
template <typename GetV>
__device__ __forceinline__ void histFindBin(GetV getv, int k, int tid,
                                            int* hist /*8192*/, int* wt /*NW*/,
                                            int* ibc /*4*/,
                                            unsigned& prefixOut, int& prevShiftOut,
                                            int& kremOut) {
  const int lane = tid & 63, wid = tid >> 6;
  int shift = 19, prevShift = 32;
  unsigned prefix = 0;
  int krem = k;
  for (;;) {
    int4* h4 = (int4*)hist;
    h4[tid] = make_int4(0, 0, 0, 0);
    h4[tid + 1024] = make_int4(0, 0, 0, 0);
    __syncthreads();
#pragma unroll
    for (int j = 0; j < 32; ++j) {
      unsigned key = fkey(getv(j));
      bool ok = (prevShift >= 32) || ((key >> prevShift) == prefix);
      if (ok) atomicAdd(&hist[(key >> shift) & 8191], 1);
    }
    __syncthreads();
    int bcnt[8];
    int L = 0;
#pragma unroll
    for (int j = 0; j < 8; ++j) { bcnt[j] = hist[8 * tid + j]; L += bcnt[j]; }
    int S = L;
#pragma unroll
    for (int off = 1; off < 64; off <<= 1) {
      int y = __shfl_down(S, off);
      S += (lane + off < 64) ? y : 0;
    }
    if (lane == 0) wt[wid] = S;
    __syncthreads();
    int aboveW = 0;
    for (int w = wid + 1; w < NW; ++w) aboveW += wt[w];
    const int R = S + aboveW;
    const int aboveR = R - L;
    if (aboveR < krem && krem <= R) {
      int above = aboveR;
      int bsel = -1, csel = 0;
#pragma unroll
      for (int j = 7; j >= 0; --j) {
        if (bsel < 0) {
          if (above + bcnt[j] >= krem) { bsel = 8 * tid + j; csel = bcnt[j]; }
          else above += bcnt[j];
        }
      }
      ibc[0] = bsel; ibc[1] = krem - above; ibc[2] = csel;
    }
    __syncthreads();
    const int bstar = ibc[0];
    krem = ibc[1];
    const int cntT = ibc[2];
    const int gap = prevShift - shift;
    prefix = (prefix << gap) | ((unsigned)bstar & ((1u << gap) - 1u));
    prevShift = shift;
    if (cntT <= 64 || shift == 0) break;
    shift = (shift >= 13) ? (shift - 13) : 0;
    __syncthreads();   // all ibc reads done before re-zeroing hist
  }
  prefixOut = prefix; prevShiftOut = prevShift; kremOut = krem;
}

// ---------------- kernel 0: gather prx, build A' = [features; mem[prx]] ----------------
__global__ void prep_kernel(const float* __restrict__ features,
                            const int* __restrict__ targets,
                            const int* __restrict__ all_prx,
                            const float* __restrict__ mem,
                            float* __restrict__ A2,
                            int* __restrict__ prxArr) {
  const int b = blockIdx.x;
  const int k = threadIdx.x;
  const int t = targets[b];
  const int pr = all_prx[t];
  if (k == 0) prxArr[b] = pr;
  A2[b * D_DIM + k] = features[b * D_DIM + k];
  A2[(B_SZ + b) * D_DIM + k] = mem[(size_t)pr * D_DIM + k];
}

// ---------------- kernel 1: split-fp16 3-pass MFMA GEMM ----------------
__global__ __launch_bounds__(256) void gemm_mfma(const float* __restrict__ A,
                                                 const float* __restrict__ Bm,
                                                 float* __restrict__ Co) {
  __shared__ _Float16 Ah[128][32], Al[128][32], Bh[128][32], Bl[128][32];
  const int tid = threadIdx.x;
  const int lane = tid & 63;
  const int wid = tid >> 6;
  const int wr = wid >> 1, wc = wid & 1;
  const int orig = (blockIdx.x & 7) * 128 + (blockIdx.x >> 3);
  const int rowBase = (orig & 3) << 7;
  const int colBase = (orig >> 2) << 7;

  const int trow = tid >> 3;
  const int tseg = tid & 7;

  floatx4 acc[4][4];
#pragma unroll
  for (int i = 0; i < 4; ++i)
#pragma unroll
    for (int j = 0; j < 4; ++j) {
      acc[i][j][0] = 0.f; acc[i][j][1] = 0.f; acc[i][j][2] = 0.f; acc[i][j][3] = 0.f;
    }

  const int fr = lane & 15;
  const int kg = (lane >> 4) << 3;

  for (int step = 0; step < 8; ++step) {
    const int k0 = step << 5;
    float4 sa[4], sb[4];
#pragma unroll
    for (int p = 0; p < 4; ++p) {
      const int r = trow + (p << 5);
      sa[p] = *(const float4*)(A  + (size_t)(rowBase + r) * D_DIM + k0 + tseg * 4);
      sb[p] = *(const float4*)(Bm + (size_t)(colBase + r) * D_DIM + k0 + tseg * 4);
    }
    __syncthreads();
#pragma unroll
    for (int p = 0; p < 4; ++p) {
      const int r = trow + (p << 5);
      float4 v = sa[p];
      half4v h, l;
      h[0] = (_Float16)v.x; l[0] = (_Float16)(v.x - (float)h[0]);
      h[1] = (_Float16)v.y; l[1] = (_Float16)(v.y - (float)h[1]);
      h[2] = (_Float16)v.z; l[2] = (_Float16)(v.z - (float)h[2]);
      h[3] = (_Float16)v.w; l[3] = (_Float16)(v.w - (float)h[3]);
      *(half4v*)&Ah[r][tseg * 4] = h;
      *(half4v*)&Al[r][tseg * 4] = l;
      v = sb[p];
      h[0] = (_Float16)v.x; l[0] = (_Float16)(v.x - (float)h[0]);
      h[1] = (_Float16)v.y; l[1] = (_Float16)(v.y - (float)h[1]);
      h[2] = (_Float16)v.z; l[2] = (_Float16)(v.z - (float)h[2]);
      h[3] = (_Float16)v.w; l[3] = (_Float16)(v.w - (float)h[3]);
      *(half4v*)&Bh[r][tseg * 4] = h;
      *(half4v*)&Bl[r][tseg * 4] = l;
    }
    __syncthreads();
    half8 ah[4], al[4], bh[4], bl[4];
#pragma unroll
    for (int f = 0; f < 4; ++f) {
      ah[f] = *(const half8*)&Ah[wr * 64 + f * 16 + fr][kg];
      al[f] = *(const half8*)&Al[wr * 64 + f * 16 + fr][kg];
      bh[f] = *(const half8*)&Bh[wc * 64 + f * 16 + fr][kg];
      bl[f] = *(const half8*)&Bl[wc * 64 + f * 16 + fr][kg];
    }
#pragma unroll
    for (int fm = 0; fm < 4; ++fm)
#pragma unroll
      for (int fn = 0; fn < 4; ++fn) {
        acc[fm][fn] = __builtin_amdgcn_mfma_f32_16x16x32_f16(ah[fm], bh[fn], acc[fm][fn], 0, 0, 0);
        acc[fm][fn] = __builtin_amdgcn_mfma_f32_16x16x32_f16(ah[fm], bl[fn], acc[fm][fn], 0, 0, 0);
        acc[fm][fn] = __builtin_amdgcn_mfma_f32_16x16x32_f16(al[fm], bh[fn], acc[fm][fn], 0, 0, 0);
      }
  }
  const int rsub = (lane >> 4) << 2;
#pragma unroll
  for (int fm = 0; fm < 4; ++fm)
#pragma unroll
    for (int fn = 0; fn < 4; ++fn) {
      const int r0 = rowBase + wr * 64 + fm * 16 + rsub;
      const int c0 = colBase + wc * 64 + fn * 16 + fr;
#pragma unroll
      for (int r = 0; r < 4; ++r)
        Co[(size_t)(r0 + r) * P_CNT + c0] = acc[fm][fn][r];
    }
}

// ---------------- kernel 2: per-sample losses — register row + fused hist select ----
// Thread owns p(j) = 4*tid + 4096*(j>>2) + (j&3), j in [0,32).
__global__ __launch_bounds__(NTHR) void persample(const float* __restrict__ OUT,
                                                  const int* __restrict__ cams,
                                                  const int* __restrict__ prxArr,
                                                  float* __restrict__ intraArr,
                                                  float* __restrict__ crossArr,
                                                  float* __restrict__ onlArr) {
  __shared__ int   hist[8192];     // 32 KiB
  __shared__ int   wt[NW];
  __shared__ int   ibc[4];
  __shared__ float bufV[64];
  __shared__ int   bufI[64];
  __shared__ int   cntS[4];
  __shared__ float redW[NW];
  __shared__ float sv[64];
  __shared__ int   si[64];
  __shared__ float cvW[NW * 8];
  __shared__ int   ciW[NW * 8];
  __shared__ float mw[NW], sw[NW];

  const int b = blockIdx.x;
  const int tid = threadIdx.x;
  const int lane = tid & 63, wid = tid >> 6;
  const float* Srow = OUT + (size_t)b * P_CNT;
  const float* Mrow = OUT + (size_t)(B_SZ + b) * P_CNT;
  const int pr = prxArr[b];
  const int cam = cams[b];
  const int base4 = tid << 2;

  // ---- load score row into registers (coalesced float4) ----
  float s[32];
#pragma unroll
  for (int q = 0; q < 8; ++q) {
    float4 f = ((const float4*)Srow)[tid + (q << 10)];
    s[4 * q + 0] = f.x; s[4 * q + 1] = f.y; s[4 * q + 2] = f.z; s[4 * q + 3] = f.w;
  }
  float pmax = NEG_BIG;
#pragma unroll
  for (int j = 0; j < 32; ++j) pmax = fmaxf(pmax, s[j]);
  const float M = blockMax(pmax, tid, redW);

  // ---- intra: online LSE over {p : p%8==cam} ----
  {
    const bool mine = ((tid & 1) == (cam >> 2));
    const int cc = cam & 3;
    float im = NEG_BIG, is = 0.f;
    if (mine) {
#pragma unroll
      for (int q = 0; q < 8; ++q) {
        float v = (cc == 0) ? s[4 * q] : (cc == 1) ? s[4 * q + 1]
                : (cc == 2) ? s[4 * q + 2] : s[4 * q + 3];
        if (v <= im) is += expf((v - im) * INVT);
        else { is = is * expf((im - v) * INVT) + 1.f; im = v; }
      }
    }
#pragma unroll
    for (int off = 1; off < 64; off <<= 1) {
      float m2 = __shfl_xor(im, off);
      float s2 = __shfl_xor(is, off);
      float Mx = fmaxf(im, m2);
      is = is * expf((im - Mx) * INVT) + s2 * expf((m2 - Mx) * INVT);
      im = Mx;
    }
    if (lane == 0) { mw[wid] = im; sw[wid] = is; }
  }
  const int posBase = pr & ~7;
  if (tid < 8) sv[tid] = Srow[posBase + tid];
  __syncthreads();
  if (tid == 0) {
    float m0 = mw[0], s0 = sw[0];
    for (int w = 1; w < NW; ++w) {
      float Mx = fmaxf(m0, mw[w]);
      s0 = s0 * expf((m0 - Mx) * INVT) + sw[w] * expf((mw[w] - Mx) * INVT);
      m0 = Mx;
    }
    intraArr[b] = -((Srow[pr] - m0) * INVT - logf(s0));
  }

  // ---- cross: exclude pos, exact 50th via hist bin + rank, fused LSE ----
  auto crossVal = [&](int j) -> float {
    int p = base4 + ((j >> 2) << 12) + (j & 3);
    return ((unsigned)(p - posBase) < 8u) ? NEG_BIG : s[j];
  };
  {
    unsigned prefix; int prevShift, krem;
    histFindBin(crossVal, 50, tid, hist, wt, ibc, prefix, prevShift, krem);
    if (tid == 0) cntS[0] = 0;
    __syncthreads();
    float seAbove = 0.f;
#pragma unroll
    for (int j = 0; j < 32; ++j) {
      float v = crossVal(j);
      unsigned keyTop = fkey(v) >> prevShift;
      if (keyTop > prefix) seAbove += expf((v - M) * INVT);
      else if (keyTop == prefix) {
        int p = atomicAdd(&cntS[0], 1);
        if (p < 64) bufV[p] = v;
      }
    }
    seAbove = blockSum(seAbove, tid, redW);   // barrier also publishes bufV/cntS
    if (tid < 64) {
      const int n = min(cntS[0], 64);
      const bool valid = (tid < n);
      float vl = valid ? bufV[tid] : NEG_BIG;
      int r = 0, eq = 0;
      for (int m2 = 0; m2 < 64; ++m2) {
        float vm = (m2 < n) ? bufV[m2] : NEG_BIG;
        r += (vm > vl); eq += (vm == vl);
      }
      unsigned long long mb = __ballot(valid && r < krem && krem <= r + eq);
      int selLane = (mb == 0) ? 0 : (int)__ffsll(mb) - 1;
      float vk = __shfl(vl, selLane);
      int rAbove = __shfl(r, selLane);
      float e = (valid && vl > vk) ? expf((vl - M) * INVT) : 0.f;
#pragma unroll
      for (int off = 1; off < 64; off <<= 1) e += __shfl_xor(e, off);
      if (tid == 0) {
        float stot = seAbove + e + (float)(krem - rAbove) * expf((vk - M) * INVT);
        float acc = 0.f;
        for (int p = 0; p < 8; ++p) stot += expf((sv[p] - M) * INVT);
        float lse = logf(stot);
        for (int p = 0; p < 8; ++p) acc += (sv[p] - M) * INVT - lse;
        crossArr[b] = -acc * 0.125f;
      }
    }
  }

  // ---- sims in place: s := 0.15*score + 0.85*memsim ----
#pragma unroll
  for (int q = 0; q < 8; ++q) {
    float4 m2 = ((const float4*)Mrow)[tid + (q << 10)];
    s[4 * q + 0] = 0.15f * s[4 * q + 0] + 0.85f * m2.x;
    s[4 * q + 1] = 0.15f * s[4 * q + 1] + 0.85f * m2.y;
    s[4 * q + 2] = 0.15f * s[4 * q + 2] + 0.85f * m2.z;
    s[4 * q + 3] = 0.15f * s[4 * q + 3] + 0.85f * m2.w;
  }

  // ---- per-camera argmax: thread parity covers 4 of 8 cameras ----
  {
    float cm[4] = {NEG_BIG, NEG_BIG, NEG_BIG, NEG_BIG};
    int cix[4] = {0x7fffffff, 0x7fffffff, 0x7fffffff, 0x7fffffff};
#pragma unroll
    for (int q = 0; q < 8; ++q) {
#pragma unroll
      for (int c = 0; c < 4; ++c) {
        float v = s[4 * q + c];
        int p = base4 + (q << 12) + c;
        if (v > cm[c]) { cm[c] = v; cix[c] = p; }
      }
    }
    const bool odd = (tid & 1);
    float v8[8]; int i8[8];
#pragma unroll
    for (int c = 0; c < 4; ++c) {
      float ov = __shfl_xor(cm[c], 1); int oi = __shfl_xor(cix[c], 1);
      v8[c]     = odd ? ov : cm[c];   i8[c]     = odd ? oi : cix[c];
      v8[c + 4] = odd ? cm[c] : ov;   i8[c + 4] = odd ? cix[c] : oi;
    }
#pragma unroll
    for (int off = 2; off <= 32; off <<= 1) {
#pragma unroll
      for (int c = 0; c < 8; ++c) {
        float vv = __shfl_xor(v8[c], off);
        int   ii = __shfl_xor(i8[c], off);
        if (vv > v8[c] || (vv == v8[c] && ii < i8[c])) { v8[c] = vv; i8[c] = ii; }
      }
    }
    if (lane < 8) {
#pragma unroll
      for (int c = 0; c < 8; ++c)
        if (lane == c) { cvW[wid * 8 + c] = v8[c]; ciW[wid * 8 + c] = i8[c]; }
    }
    __syncthreads();
    if (tid < 8) {
      float v = cvW[tid]; int ix = ciW[tid];
      for (int w = 1; w < NW; ++w) {
        float v2 = cvW[w * 8 + tid]; int i2 = ciW[w * 8 + tid];
        if (v2 > v || (v2 == v && i2 < ix)) { v = v2; ix = i2; }
      }
      cvW[tid] = v; ciW[tid] = ix;
    }
    __syncthreads();
    if (tid == 0) {
      unsigned used = 0;
      for (int k = 0; k < 3; ++k) {
        float best = NEG_BIG; int bc = 0;
        for (int c = 0; c < 8; ++c)
          if (!((used >> c) & 1u) && cvW[c] > best) { best = cvW[c]; bc = c; }
        used |= 1u << bc;
        si[k] = ciW[bc];
      }
    }
    __syncthreads();
  }
  const int c0 = si[0], c1 = si[1], c2 = si[2];
  __syncthreads();

  // ---- online: exclude chosen; exact 50th via hist bin + rank; fused index collect ----
  auto simsVal = [&](int j) -> float {
    int p = base4 + ((j >> 2) << 12) + (j & 3);
    return (p == c0 || p == c1 || p == c2) ? NEG_BIG : s[j];
  };
  {
    unsigned prefix; int prevShift, krem;
    histFindBin(simsVal, 50, tid, hist, wt, ibc, prefix, prevShift, krem);
    if (tid == 0) { cntS[0] = 0; cntS[1] = 3; }   // si[0..3) hold chosen
    __syncthreads();
#pragma unroll
    for (int j = 0; j < 32; ++j) {
      float v = simsVal(j);
      int p = base4 + ((j >> 2) << 12) + (j & 3);
      unsigned keyTop = fkey(v) >> prevShift;
      if (keyTop > prefix) {
        int t = atomicAdd(&cntS[1], 1);
        si[t] = p;                      // strictly above bin => in top-50 for sure
      } else if (keyTop == prefix) {
        int t = atomicAdd(&cntS[0], 1);
        if (t < 64) { bufV[t] = v; bufI[t] = p; }
      }
    }
    __syncthreads();
    if (tid < 64) {
      const int n = min(cntS[0], 64);
      const bool valid = (tid < n);
      float vl = valid ? bufV[tid] : NEG_BIG;
      int il = valid ? bufI[tid] : 0x7fffffff;
      int r = 0, eq = 0, ti = 0;
      for (int m2 = 0; m2 < 64; ++m2) {
        float vm = (m2 < n) ? bufV[m2] : NEG_BIG;
        int im = (m2 < n) ? bufI[m2] : 0x7fffffff;
        r += (vm > vl); eq += (vm == vl);
        ti += (vm == vl && im < il);
      }
      unsigned long long mb = __ballot(valid && r < krem && krem <= r + eq);
      int selLane = (mb == 0) ? 0 : (int)__ffsll(mb) - 1;
      float vk = __shfl(vl, selLane);
      int rAbove = __shfl(r, selLane);
      int tcnt = krem - rAbove;        // ties at vk to include, smallest indices first
      bool take = valid && ((vl > vk) || (vl == vk && ti < tcnt));
      if (take) {
        int t = atomicAdd(&cntS[1], 1);
        si[t] = il;
      }
      // wave 0 proceeds to gather + LSE (si writes are wave-internal, ordered)
      float v = NEG_BIG;
      if (tid < 53) v = Srow[si[tid]];
      float mm = v;
#pragma unroll
      for (int off = 1; off < 64; off <<= 1) mm = fmaxf(mm, __shfl_xor(mm, off));
      float e = (tid < 53) ? expf((v - mm) * INVT) : 0.f;
      float ss = e;
#pragma unroll
      for (int off = 1; off < 64; off <<= 1) ss += __shfl_xor(ss, off);
      float lse = logf(ss);
      float c = (tid < 3) ? ((v - mm) * INVT - lse) : 0.f;
#pragma unroll
      for (int off = 1; off < 64; off <<= 1) c += __shfl_xor(c, off);
      if (tid == 0) onlArr[b] = -c * (1.0f / 3.0f);
    }
  }
}

// ---------------- kernel 3: per-camera means -> scalar ----------------
__global__ void finalize(const int* __restrict__ cams,
                         const float* __restrict__ ia,
                         const float* __restrict__ ca,
                         const float* __restrict__ oa,
                         float* __restrict__ out) {
  if (blockIdx.x == 0 && threadIdx.x == 0) {
    float s[8] = {}; float n[8] = {};
    for (int b = 0; b < B_SZ; ++b) {
      int c = cams[b];
      s[c] += ia[b] + ca[b] + oa[b];
      n[c] += 1.f;
    }
    float tot = 0.f;
    for (int c = 0; c < 8; ++c)
      if (n[c] > 0.f) tot += s[c] / n[c];
    out[0] = tot;
  }
}

extern "C" void kernel_launch(void* const* d_in, const int* in_sizes, int n_in,
                              void* d_out, int out_size, void* d_ws, size_t ws_size,
                              hipStream_t stream) {
  const float* features = (const float*)d_in[0];
  const int*   targets  = (const int*)d_in[1];
  const int*   cams     = (const int*)d_in[2];
  const float* mem      = (const float*)d_in[4];
  const int*   all_prx  = (const int*)d_in[6];

  float* ws = (float*)d_ws;
  float* A2  = ws;                               // 512*256
  float* OUT = ws + 512 * D_DIM;                 // 512*32768
  float* tail = OUT + (size_t)512 * P_CNT;
  int*   prxArr  = (int*)tail;                   // 256
  float* intraArr = (float*)(prxArr + B_SZ);     // 256
  float* crossArr = intraArr + B_SZ;             // 256
  float* onlArr   = crossArr + B_SZ;             // 256

  prep_kernel<<<B_SZ, D_DIM, 0, stream>>>(features, targets, all_prx, mem, A2, prxArr);
  gemm_mfma<<<1024, 256, 0, stream>>>(A2, mem, OUT);
  persample<<<B_SZ, NTHR, 0, stream>>>(OUT, cams, prxArr, intraArr, crossArr, onlArr);
  finalize<<<1, 64, 0, stream>>>(cams, intraArr, crossArr, onlArr, (float*)d_out);
}